// Round 3
// baseline (97574.744 us; speedup 1.0000x reference)
//
#include <hip/hip_runtime.h>
#include <cstdint>
#include <cstddef>

// Problem constants
constexpr int B_ = 16, T_ = 200, L_ = 250;
constexpr int IDIM = 512, ODIM = 80, DUNITS = 1024;
constexpr int ADIM = 128, ACH = 32, AK = 31;
constexpr int PRE = 256;
constexpr int TPAD = 208;   // T padded to 13*16 for MFMA t-tiles
constexpr int NBLK = 256;   // persistent grid = #CUs

typedef _Float16 h16;
typedef _Float16 half8 __attribute__((ext_vector_type(8)));
typedef _Float16 half4 __attribute__((ext_vector_type(4)));
typedef _Float16 half2v __attribute__((ext_vector_type(2)));
typedef float f32x4 __attribute__((ext_vector_type(4)));

// ---- workspace byte offsets (16B-aligned) ----
constexpr size_t OFF_PE    = 0;         // pe_h   [16][128][208] f16
constexpr size_t OFF_H0H   = 851968;    // h0h    [2][16][1024] f16
constexpr size_t OFF_Z1H   = 917504;    // z1h    [2][16][1024] f16
constexpr size_t OFF_ATTC  = 983040;    // attc_h [16][512] f16
constexpr size_t OFF_BAR   = 999424;    // bar    [512] int
constexpr size_t ZERO_BYTES= 1001472;   // zero span [0, here)
constexpr size_t OFF_MB    = 1001472;   // Mb     [8][64][8] f16
constexpr size_t OFF_WDH   = 1009664;   // Wdh    [1024][128] f16
constexpr size_t OFF_PREN  = 1271808;   // pren_h [250][16][256] f16
constexpr size_t OFF_HSH   = 3319808;   // hs_h   [16][200][512] f16
constexpr size_t OFF_W0H   = 6596608;   // W0h    [4096][1792] f16 (rows u*4+g)
constexpr size_t OFF_W1H   = 21276672;  // W1h    [4096][2048] f16 (rows u*4+g)
constexpr size_t OFF_Z1ALL = 38053888;  // z1all  [250][16][1024] f32
constexpr size_t OFF_OUTS  = 54437888;  // outs   [16][80][250] f32
constexpr size_t OFF_PA    = 55717888;  // postnet ping [16][512][250] f32
constexpr size_t OFF_PB    = 63909888;  // postnet pong

__device__ __forceinline__ float fsig(float x) {
  x = fminf(fmaxf(x, -30.f), 30.f);
  return __builtin_amdgcn_rcpf(1.f + __expf(-x));
}
__device__ __forceinline__ float ftanh(float x) {
  x = fminf(fmaxf(x, -15.f), 15.f);
  const float e = __expf(2.f * x);
  return (e - 1.f) * __builtin_amdgcn_rcpf(e + 1.f);
}
__device__ __forceinline__ f32x4 mfma16(half8 a, half8 b, f32x4 c) {
  return __builtin_amdgcn_mfma_f32_16x16x32_f16(a, b, c, 0, 0, 0);
}

// ---------------- prep kernels ----------------

__global__ void k_zero(float4* __restrict__ p, int n4) {
  const int i = blockIdx.x * blockDim.x + threadIdx.x;
  if (i < n4) p[i] = make_float4(0.f, 0.f, 0.f, 0.f);
}

__global__ void __launch_bounds__(128) k_preenc(const float* __restrict__ hs,
    const float* __restrict__ W_enc, const float* __restrict__ b_enc,
    h16* __restrict__ pe_h) {
  const int bt = blockIdx.x, b = bt / T_, tt = bt % T_;
  __shared__ float s[IDIM];
  for (int i = threadIdx.x; i < IDIM; i += 128) s[i] = hs[(size_t)bt * IDIM + i];
  __syncthreads();
  const int a = threadIdx.x;
  float acc = b_enc[a];
#pragma unroll 4
  for (int d = 0; d < IDIM; ++d) acc += s[d] * W_enc[d * ADIM + a];
  pe_h[((size_t)b * ADIM + a) * TPAD + tt] = (h16)acc;
}

// Mb: M[k][a] = sum_c lconv[c][k] W_att[c][a], packed in MFMA B-frag order
__global__ void k_precMb(const float* __restrict__ lconv, const float* __restrict__ W_att,
                         h16* __restrict__ Mb) {
  const int at = blockIdx.x, lane = threadIdx.x;   // 8 blocks x 64 threads
  const int a = at * 16 + (lane & 15);
  const int k0 = (lane >> 4) * 8;
  half8 o;
#pragma unroll
  for (int j = 0; j < 8; ++j) {
    const int k = k0 + j;
    float v = 0.f;
    if (k < AK)
      for (int c = 0; c < ACH; ++c) v += lconv[c * AK + k] * W_att[c * ADIM + a];
    o[j] = (h16)v;
  }
  *(half8*)(Mb + (size_t)(at * 64 + lane) * 8) = o;
}

__global__ void k_cvt_w0(const float* __restrict__ Wih0, const float* __restrict__ Whh0,
                         h16* __restrict__ W0h) {
  const int rr = blockIdx.x;
  const int u = rr >> 2, g = rr & 3;
  const int orig = g * 1024 + u;
  const float* ih = Wih0 + (size_t)orig * 768;
  const float* hh = Whh0 + (size_t)orig * 1024;
  h16* out = W0h + (size_t)rr * 1792;
  for (int k = threadIdx.x; k < 1792; k += 256)
    out[k] = (h16)(k < 768 ? ih[k] : hh[k - 768]);
}

__global__ void k_cvt_w1(const float* __restrict__ Wih1, const float* __restrict__ Whh1,
                         h16* __restrict__ W1h) {
  const int rr = blockIdx.x;
  const int u = rr >> 2, g = rr & 3;
  const int orig = g * 1024 + u;
  const float* ih = Wih1 + (size_t)orig * 1024;
  const float* hh = Whh1 + (size_t)orig * 1024;
  h16* out = W1h + (size_t)rr * 2048;
  for (int k = threadIdx.x; k < 2048; k += 256)
    out[k] = (h16)(k < 1024 ? ih[k] : hh[k - 1024]);
}

__global__ void k_cvt_f32f16(const float* __restrict__ src, h16* __restrict__ dst) {
  const size_t i = ((size_t)blockIdx.x * 256 + threadIdx.x) * 4;
  const float4 v = *(const float4*)(src + i);
  half4 o; o[0] = (h16)v.x; o[1] = (h16)v.y; o[2] = (h16)v.z; o[3] = (h16)v.w;
  *(half4*)(dst + i) = o;
}

__global__ void k_prenet1(const float* __restrict__ ys, const float* __restrict__ W1,
                          float* __restrict__ h1) {
  const int bl = blockIdx.x, b = bl / L_, l = bl % L_;
  __shared__ float s[ODIM];
  if (threadIdx.x < ODIM)
    s[threadIdx.x] = (l == 0) ? 0.f : ys[((size_t)b * L_ + l - 1) * ODIM + threadIdx.x];
  __syncthreads();
  const int p = threadIdx.x;
  float acc = 0.f;
#pragma unroll 4
  for (int o = 0; o < ODIM; ++o) acc += s[o] * W1[o * PRE + p];
  h1[(size_t)bl * PRE + p] = fmaxf(acc, 0.f);
}

__global__ void k_prenet2h(const float* __restrict__ h1, const float* __restrict__ W2,
                           h16* __restrict__ pren_h) {
  const int bl = blockIdx.x, b = bl / L_, ll = bl % L_;
  __shared__ float s[PRE];
  s[threadIdx.x] = h1[(size_t)bl * PRE + threadIdx.x];
  __syncthreads();
  const int p = threadIdx.x;
  float acc = 0.f;
#pragma unroll 4
  for (int o = 0; o < PRE; ++o) acc += s[o] * W2[o * PRE + p];
  pren_h[((size_t)ll * B_ + b) * PRE + p] = (h16)fmaxf(acc, 0.f);
}

// ---------------- persistent scan kernel ----------------

struct ScanArgs {
  const h16 *W0h, *W1h, *Wdh, *pe_h, *Mb, *hs_h, *pren_h;
  h16 *h0h, *z1h, *attc;
  const float *b0, *b1, *gvw;
  const int *hlens;
  float *z1all;
  int *bar;
};

__device__ __forceinline__ void gbar(int* bar, int idx) {
  __syncthreads();
  if (threadIdx.x == 0) {
    __hip_atomic_fetch_add(bar + idx, 1, __ATOMIC_RELEASE, __HIP_MEMORY_SCOPE_AGENT);
    while (__hip_atomic_load(bar + idx, __ATOMIC_ACQUIRE, __HIP_MEMORY_SCOPE_AGENT) < NBLK) {
      __builtin_amdgcn_s_sleep(1);
    }
  }
  __syncthreads();
}

// attention producing attc(t+1): reads z0(t) from h0h[(t&1)^1], attw state in s_aw
__device__ void att_step(const int t, const int b, const int hl, const ScanArgs& A,
                         const half8* bfrag, float* s_aw, float* s_dp, float* s_gv,
                         float* s_ew, float* s_wt, float (*s_dpp)[ADIM],
                         h16* s_z0h, float* s_r8, float* s_bc) {
  const int tid = threadIdx.x;
  const int lane = tid & 63, wave = tid >> 6;
  const int l15 = lane & 15;
  const int po = (t & 1) ^ 1;   // t=-1 -> 0 (zeros)
  // ---- dp = z0 @ W_dec (f16 weights, f32 accum) ----
  if (tid < 128) *(half8*)(s_z0h + tid * 8) =
      *(const half8*)(A.h0h + (size_t)po * (B_ * DUNITS) + b * DUNITS + tid * 8);
  __syncthreads();
  {
    const int a0 = (tid & 63) * 2, kq = tid >> 6;
    float d0 = 0.f, d1 = 0.f;
    const h16* wp = A.Wdh + (size_t)(kq * 256) * ADIM + a0;
#pragma unroll 8
    for (int k = 0; k < 256; ++k) {
      const float z = (float)s_z0h[kq * 256 + k];
      const half2v wv = *(const half2v*)(wp + (size_t)k * ADIM);
      d0 += z * (float)wv[0]; d1 += z * (float)wv[1];
    }
    s_dpp[kq][a0] = d0; s_dpp[kq][a0 + 1] = d1;
  }
  __syncthreads();
  if (tid < ADIM) s_dp[tid] = s_dpp[0][tid] + s_dpp[1][tid] + s_dpp[2][tid] + s_dpp[3][tid];
  __syncthreads();
  // ---- scores: conv via MFMA + fused tanh-dot ----
#pragma unroll
  for (int mi = 0; mi < 4; ++mi) {
    const int mt = wave + mi * 4;
    if (mt <= 12) {
      half8 af;
#pragma unroll
      for (int j = 0; j < 8; ++j) af[j] = (h16)s_aw[mt * 16 + l15 + (lane >> 4) * 8 + j];
      const int t0 = mt * 16 + 4 * (lane >> 4);
      float e0 = 0.f, e1 = 0.f, e2 = 0.f, e3 = 0.f;
#pragma unroll
      for (int at = 0; at < 8; ++at) {
        f32x4 z4 = {0.f, 0.f, 0.f, 0.f};
        const f32x4 cv = mfma16(af, bfrag[at], z4);
        const int a = at * 16 + l15;
        const half4 pe4 = *(const half4*)(A.pe_h + ((size_t)b * ADIM + a) * TPAD + t0);
        const float g = s_gv[a], d = s_dp[a];
        e0 += g * ftanh(cv[0] + (float)pe4[0] + d);
        e1 += g * ftanh(cv[1] + (float)pe4[1] + d);
        e2 += g * ftanh(cv[2] + (float)pe4[2] + d);
        e3 += g * ftanh(cv[3] + (float)pe4[3] + d);
      }
#pragma unroll
      for (int o = 1; o < 16; o <<= 1) {
        e0 += __shfl_xor(e0, o); e1 += __shfl_xor(e1, o);
        e2 += __shfl_xor(e2, o); e3 += __shfl_xor(e3, o);
      }
      if (l15 == 0) {
        s_ew[t0 + 0] = e0; s_ew[t0 + 1] = e1; s_ew[t0 + 2] = e2; s_ew[t0 + 3] = e3;
      }
    }
  }
  __syncthreads();
  // ---- softmax over t (scale 2.0; gvec_b cancels) ----
  const float val = (tid < hl) ? 2.f * s_ew[tid] : -3.0e38f;
  float m = val;
#pragma unroll
  for (int o = 32; o > 0; o >>= 1) m = fmaxf(m, __shfl_xor(m, o));
  if ((tid & 63) == 0) s_r8[tid >> 6] = m;
  __syncthreads();
  if (tid == 0) s_bc[0] = fmaxf(fmaxf(s_r8[0], s_r8[1]), fmaxf(s_r8[2], s_r8[3]));
  __syncthreads();
  const float p = (tid < hl) ? __expf(val - s_bc[0]) : 0.f;
  float ssum = p;
#pragma unroll
  for (int o = 32; o > 0; o >>= 1) ssum += __shfl_xor(ssum, o);
  if ((tid & 63) == 0) s_r8[4 + (tid >> 6)] = ssum;
  __syncthreads();
  if (tid == 0) s_bc[1] = __builtin_amdgcn_rcpf(s_r8[4] + s_r8[5] + s_r8[6] + s_r8[7]);
  __syncthreads();
  if (tid < T_) {
    const float w = p * s_bc[1];
    s_wt[tid] = w;
    s_aw[15 + tid] = w;   // update attw state in place (halo stays 0)
  }
  __syncthreads();
  // ---- context ----
  const h16* hsb = A.hs_h + (size_t)b * T_ * IDIM;
  float cx0 = 0.f, cx1 = 0.f;
#pragma unroll 4
  for (int tt = 0; tt < hl; ++tt) {
    const float w = s_wt[tt];
    const half2v hv = *(const half2v*)(hsb + (size_t)tt * IDIM + 2 * tid);
    cx0 += w * (float)hv[0];
    cx1 += w * (float)hv[1];
  }
  half2v o2; o2[0] = (h16)cx0; o2[1] = (h16)cx1;
  *(half2v*)(A.attc + b * IDIM + 2 * tid) = o2;
}

__global__ void __launch_bounds__(256, 1) k_scan(const ScanArgs A) {
  __shared__ float s_red[4][64][4];
  __shared__ float s_g[16][20];
  __shared__ float s_aw[240];
  __shared__ float s_dp[ADIM];
  __shared__ float s_gv[ADIM];
  __shared__ float s_ew[256];
  __shared__ float s_wt[208];
  __shared__ float s_dpp[4][ADIM];
  __shared__ h16  s_z0h[DUNITS];
  __shared__ float s_r8[8];
  __shared__ float s_bc[2];

  const int blk = blockIdx.x, tid = threadIdx.x;
  const int lane = tid & 63, wave = tid >> 6;
  const int nloc = lane & 15, kl8 = (lane >> 4) * 8;

  // ---- persistent weights in registers ----
  half8 w0r[14];
  {
    const h16* p = A.W0h + ((size_t)(blk * 16 + nloc)) * 1792 + wave * 448 + kl8;
#pragma unroll
    for (int c = 0; c < 14; ++c) w0r[c] = *(const half8*)(p + c * 32);
  }
  half8 w1r[16], w2r[16];
  if (blk >= 16) {
    const h16* p = A.W1h + ((size_t)((blk - 16) * 16 + nloc)) * 2048 + wave * 512 + kl8;
#pragma unroll
    for (int c = 0; c < 16; ++c) w1r[c] = *(const half8*)(p + c * 32);
    if (blk < 32) {
      const h16* q = A.W1h + ((size_t)((blk + 224) * 16 + nloc)) * 2048 + wave * 512 + kl8;
#pragma unroll
      for (int c = 0; c < 16; ++c) w2r[c] = *(const half8*)(q + c * 32);
    }
  }
  half8 bfrag[8];
  int hl = 0;
  if (blk < 16) {
#pragma unroll
    for (int at = 0; at < 8; ++at)
      bfrag[at] = *(const half8*)(A.Mb + (size_t)(at * 64 + lane) * 8);
    hl = A.hlens[blk];
    if (tid < ADIM) s_gv[tid] = A.gvw[tid];
    if (tid < 240) {
      const int tt = tid - (AK / 2);
      s_aw[tid] = (tt >= 0 && tt < hl) ? (1.f / (float)hl) : 0.f;
    }
    __syncthreads();
  }
  float c0reg = 0.f, c1reg = 0.f, c2reg = 0.f;
  int bi = 0;

  // pre-loop: att(0) from zero state
  if (blk < 16)
    att_step(-1, blk, hl, A, bfrag, s_aw, s_dp, s_gv, s_ew, s_wt, s_dpp, s_z0h, s_r8, s_bc);
  gbar(A.bar, bi++);

  for (int t = 0; t < L_; ++t) {
    const int pi = t & 1, po = pi ^ 1;
    // ---------- phase 1: LSTM0 (all 256 blocks) ----------
    {
      const h16* hin = A.h0h + (size_t)pi * (B_ * DUNITS);
      const h16* prent = A.pren_h + (size_t)t * (B_ * PRE);
      f32x4 acc = {0.f, 0.f, 0.f, 0.f};
#pragma unroll
      for (int c = 0; c < 14; ++c) {
        const int kg = wave * 448 + c * 32;
        const h16* ap;
        if (kg < 512)      ap = A.attc + nloc * IDIM + kg + kl8;
        else if (kg < 768) ap = prent + nloc * PRE + (kg - 512) + kl8;
        else               ap = hin + nloc * DUNITS + (kg - 768) + kl8;
        acc = mfma16(*(const half8*)ap, w0r[c], acc);
      }
#pragma unroll
      for (int r = 0; r < 4; ++r) s_red[wave][lane][r] = acc[r];
      __syncthreads();
      {
        const int l = tid & 63, r = tid >> 6;
        const float v = s_red[0][l][r] + s_red[1][l][r] + s_red[2][l][r] + s_red[3][l][r];
        s_g[l & 15][4 * (l >> 4) + r] = v;
      }
      __syncthreads();
      if (tid < 64) {
        const int ul = tid >> 4, b = tid & 15;
        const int u = blk * 4 + ul;
        const float xi = s_g[ul * 4 + 0][b] + A.b0[u];
        const float xf = s_g[ul * 4 + 1][b] + A.b0[1024 + u];
        const float xg = s_g[ul * 4 + 2][b] + A.b0[2048 + u];
        const float xo = s_g[ul * 4 + 3][b] + A.b0[3072 + u];
        const float cn = fsig(xf) * c0reg + fsig(xi) * ftanh(xg);
        c0reg = cn;
        A.h0h[(size_t)po * (B_ * DUNITS) + b * DUNITS + u] = (h16)(fsig(xo) * ftanh(cn));
      }
    }
    gbar(A.bar, bi++);
    // ---------- phase 2: att(t+1) on blocks 0-15 || LSTM1(t) on blocks 16-255 ----------
    if (blk < 16) {
      if (t + 1 < L_)
        att_step(t, blk, hl, A, bfrag, s_aw, s_dp, s_gv, s_ew, s_wt, s_dpp, s_z0h, s_r8, s_bc);
    } else {
      const h16* z0p = A.h0h + (size_t)po * (B_ * DUNITS);
      const h16* z1p = A.z1h + (size_t)pi * (B_ * DUNITS);
      // pass 1: slab blk-16
      {
        f32x4 acc = {0.f, 0.f, 0.f, 0.f};
#pragma unroll
        for (int c = 0; c < 16; ++c) {
          const int kg = wave * 512 + c * 32;
          const h16* ap = (kg < 1024) ? (z0p + nloc * DUNITS + kg + kl8)
                                      : (z1p + nloc * DUNITS + (kg - 1024) + kl8);
          acc = mfma16(*(const half8*)ap, w1r[c], acc);
        }
#pragma unroll
        for (int r = 0; r < 4; ++r) s_red[wave][lane][r] = acc[r];
        __syncthreads();
        {
          const int l = tid & 63, r = tid >> 6;
          const float v = s_red[0][l][r] + s_red[1][l][r] + s_red[2][l][r] + s_red[3][l][r];
          s_g[l & 15][4 * (l >> 4) + r] = v;
        }
        __syncthreads();
        if (tid < 64) {
          const int ul = tid >> 4, b = tid & 15;
          const int u = (blk - 16) * 4 + ul;
          const float xi = s_g[ul * 4 + 0][b] + A.b1[u];
          const float xf = s_g[ul * 4 + 1][b] + A.b1[1024 + u];
          const float xg = s_g[ul * 4 + 2][b] + A.b1[2048 + u];
          const float xo = s_g[ul * 4 + 3][b] + A.b1[3072 + u];
          const float cn = fsig(xf) * c1reg + fsig(xi) * ftanh(xg);
          c1reg = cn;
          const float hn = fsig(xo) * ftanh(cn);
          A.z1h[(size_t)po * (B_ * DUNITS) + b * DUNITS + u] = (h16)hn;
          A.z1all[((size_t)t * B_ + b) * DUNITS + u] = hn;
        }
      }
      // pass 2 (blocks 16-31): slab blk+224
      if (blk < 32) {
        f32x4 acc = {0.f, 0.f, 0.f, 0.f};
#pragma unroll
        for (int c = 0; c < 16; ++c) {
          const int kg = wave * 512 + c * 32;
          const h16* ap = (kg < 1024) ? (z0p + nloc * DUNITS + kg + kl8)
                                      : (z1p + nloc * DUNITS + (kg - 1024) + kl8);
          acc = mfma16(*(const half8*)ap, w2r[c], acc);
        }
        __syncthreads();
#pragma unroll
        for (int r = 0; r < 4; ++r) s_red[wave][lane][r] = acc[r];
        __syncthreads();
        {
          const int l = tid & 63, r = tid >> 6;
          const float v = s_red[0][l][r] + s_red[1][l][r] + s_red[2][l][r] + s_red[3][l][r];
          s_g[l & 15][4 * (l >> 4) + r] = v;
        }
        __syncthreads();
        if (tid < 64) {
          const int ul = tid >> 4, b = tid & 15;
          const int u = (blk + 224) * 4 + ul;
          const float xi = s_g[ul * 4 + 0][b] + A.b1[u];
          const float xf = s_g[ul * 4 + 1][b] + A.b1[1024 + u];
          const float xg = s_g[ul * 4 + 2][b] + A.b1[2048 + u];
          const float xo = s_g[ul * 4 + 3][b] + A.b1[3072 + u];
          const float cn = fsig(xf) * c2reg + fsig(xi) * ftanh(xg);
          c2reg = cn;
          const float hn = fsig(xo) * ftanh(cn);
          A.z1h[(size_t)po * (B_ * DUNITS) + b * DUNITS + u] = (h16)hn;
          A.z1all[((size_t)t * B_ + b) * DUNITS + u] = hn;
        }
      }
    }
    gbar(A.bar, bi++);
  }
}

// ---------------- output heads + postnet ----------------

__global__ void __launch_bounds__(128) k_heads(const float* __restrict__ z1_all,
    const float* __restrict__ feat_W, const float* __restrict__ prob_W,
    const float* __restrict__ prob_b, float* __restrict__ out1,
    float* __restrict__ probs, float* __restrict__ outs_bct) {
  const int bl = blockIdx.x, b = bl / L_, l = bl % L_;
  __shared__ float s_z[DUNITS];
  const float* z = z1_all + ((size_t)l * B_ + b) * DUNITS;
  for (int i = threadIdx.x; i < DUNITS; i += 128) s_z[i] = z[i];
  __syncthreads();
  const int co = threadIdx.x;
  if (co < ODIM) {
    float acc = 0.f;
#pragma unroll 4
    for (int d = 0; d < DUNITS; ++d) acc += s_z[d] * feat_W[d * ODIM + co];
    out1[((size_t)b * L_ + l) * ODIM + co] = acc;
    outs_bct[((size_t)b * ODIM + co) * L_ + l] = acc;
  } else if (co == 96) {
    float acc = prob_b[0];
#pragma unroll 4
    for (int d = 0; d < DUNITS; ++d) acc += s_z[d] * prob_W[d];
    probs[(size_t)b * L_ + l] = acc;
  }
}

template <bool TANH, bool FINAL>
__global__ void __launch_bounds__(256) k_conv(const float* __restrict__ x,
    const float* __restrict__ w, const float* __restrict__ gamma,
    const float* __restrict__ beta, float* __restrict__ y,
    const float* __restrict__ res, float* __restrict__ out0,
    const int Cin, const int Cout) {
  const int b = blockIdx.x;
  const int co0 = blockIdx.y * 8;
  const int tid = threadIdx.x;
  const int l = tid & 127;
  const int cg = tid >> 7;
  __shared__ float s_x[8][260];
  __shared__ float s_w[8][8][5];
  float acc[4][2] = {{0.f, 0.f}, {0.f, 0.f}, {0.f, 0.f}, {0.f, 0.f}};
  for (int ci0 = 0; ci0 < Cin; ci0 += 8) {
    __syncthreads();
    for (int i = tid; i < 8 * 260; i += 256) {
      const int ci = i / 260, col = i % 260;
      const int ll = col - 2;
      s_x[ci][col] = (ll >= 0 && ll < L_) ? x[((size_t)b * Cin + ci0 + ci) * L_ + ll] : 0.f;
    }
    for (int i = tid; i < 8 * 8 * 5; i += 256) {
      const int ci = i / 40, rem = i % 40, cl = rem / 5, k = rem % 5;
      s_w[ci][cl][k] = w[((size_t)(co0 + cl) * Cin + ci0 + ci) * 5 + k];
    }
    __syncthreads();
#pragma unroll 2
    for (int ci = 0; ci < 8; ++ci) {
      float xv0[5], xv1[5];
#pragma unroll
      for (int k = 0; k < 5; ++k) { xv0[k] = s_x[ci][l + k]; xv1[k] = s_x[ci][l + 128 + k]; }
#pragma unroll
      for (int j = 0; j < 4; ++j) {
        const int cl = cg * 4 + j;
#pragma unroll
        for (int k = 0; k < 5; ++k) {
          const float ww = s_w[ci][cl][k];
          acc[j][0] += ww * xv0[k];
          acc[j][1] += ww * xv1[k];
        }
      }
    }
  }
#pragma unroll
  for (int j = 0; j < 4; ++j) {
    const int co = co0 + cg * 4 + j;
    const float gm = gamma[co], bt = beta[co];
#pragma unroll
    for (int h = 0; h < 2; ++h) {
      const int ll = l + h * 128;
      if (ll < L_) {
        float v = gm * acc[j][h] + bt;
        if (TANH) v = ftanh(v);
        if (FINAL) out0[((size_t)b * L_ + ll) * ODIM + co] =
                       res[((size_t)b * ODIM + co) * L_ + ll] + v;
        else y[((size_t)b * Cout + co) * L_ + ll] = v;
      }
    }
  }
}

// ---------------- launch ----------------

extern "C" void kernel_launch(void* const* d_in, const int* in_sizes, int n_in,
                              void* d_out, int out_size, void* d_ws, size_t ws_size,
                              hipStream_t stream) {
  const float* hs    = (const float*)d_in[0];
  const int*   hlens = (const int*)d_in[1];
  const float* ys    = (const float*)d_in[2];
  const float* W_enc = (const float*)d_in[3];
  const float* b_enc = (const float*)d_in[4];
  const float* W_dec = (const float*)d_in[5];
  const float* W_att = (const float*)d_in[6];
  const float* lconv = (const float*)d_in[7];
  const float* gvw   = (const float*)d_in[8];
  const float* pW1   = (const float*)d_in[10];
  const float* pW2   = (const float*)d_in[11];
  const float* Wih0  = (const float*)d_in[12];
  const float* Whh0  = (const float*)d_in[13];
  const float* b0    = (const float*)d_in[14];
  const float* Wih1  = (const float*)d_in[15];
  const float* Whh1  = (const float*)d_in[16];
  const float* b1    = (const float*)d_in[17];
  const float* featW = (const float*)d_in[18];
  const float* probW = (const float*)d_in[19];
  const float* probB = (const float*)d_in[20];
  const float* pwin  = (const float*)d_in[21];
  const float* pgin  = (const float*)d_in[22];
  const float* pbin  = (const float*)d_in[23];
  const float* pwmid = (const float*)d_in[24];
  const float* pgmid = (const float*)d_in[25];
  const float* pbmid = (const float*)d_in[26];
  const float* pwout = (const float*)d_in[27];
  const float* pgout = (const float*)d_in[28];
  const float* pbout = (const float*)d_in[29];

  char* ws = (char*)d_ws;
  h16*   pe_h   = (h16*)(ws + OFF_PE);
  h16*   h0h    = (h16*)(ws + OFF_H0H);
  h16*   z1h    = (h16*)(ws + OFF_Z1H);
  h16*   attc_h = (h16*)(ws + OFF_ATTC);
  int*   bar    = (int*)(ws + OFF_BAR);
  h16*   Mb     = (h16*)(ws + OFF_MB);
  h16*   Wdh    = (h16*)(ws + OFF_WDH);
  h16*   pren_h = (h16*)(ws + OFF_PREN);
  h16*   hs_h   = (h16*)(ws + OFF_HSH);
  h16*   W0h    = (h16*)(ws + OFF_W0H);
  h16*   W1h    = (h16*)(ws + OFF_W1H);
  float* z1all  = (float*)(ws + OFF_Z1ALL);
  float* outsb  = (float*)(ws + OFF_OUTS);
  float* pa     = (float*)(ws + OFF_PA);
  float* pb     = (float*)(ws + OFF_PB);

  float* out0 = (float*)d_out;
  float* out1 = out0 + (size_t)B_ * L_ * ODIM;
  float* out2 = out1 + (size_t)B_ * L_ * ODIM;

  // prep
  hipLaunchKernelGGL(k_zero, dim3((ZERO_BYTES / 16 + 255) / 256), dim3(256), 0, stream,
                     (float4*)ws, (int)(ZERO_BYTES / 16));
  hipLaunchKernelGGL(k_preenc, dim3(B_ * T_), dim3(128), 0, stream, hs, W_enc, b_enc, pe_h);
  hipLaunchKernelGGL(k_precMb, dim3(8), dim3(64), 0, stream, lconv, W_att, Mb);
  hipLaunchKernelGGL(k_cvt_w0, dim3(4096), dim3(256), 0, stream, Wih0, Whh0, W0h);
  hipLaunchKernelGGL(k_cvt_w1, dim3(4096), dim3(256), 0, stream, Wih1, Whh1, W1h);
  hipLaunchKernelGGL(k_cvt_f32f16, dim3(128), dim3(256), 0, stream, W_dec, Wdh);
  hipLaunchKernelGGL(k_cvt_f32f16, dim3(1600), dim3(256), 0, stream, hs, hs_h);
  hipLaunchKernelGGL(k_prenet1, dim3(B_ * L_), dim3(PRE), 0, stream, ys, pW1, pa);
  hipLaunchKernelGGL(k_prenet2h, dim3(B_ * L_), dim3(PRE), 0, stream, pa, pW2, pren_h);

  // persistent scan (single launch, 501 grid barriers)
  ScanArgs SA{W0h, W1h, Wdh, pe_h, Mb, hs_h, pren_h,
              h0h, z1h, attc_h, b0, b1, gvw, hlens, z1all, bar};
  hipLaunchKernelGGL(k_scan, dim3(NBLK), dim3(256), 0, stream, SA);

  hipLaunchKernelGGL(k_heads, dim3(B_ * L_), dim3(128), 0, stream,
                     z1all, featW, probW, probB, out1, out2, outsb);

  hipLaunchKernelGGL((k_conv<true, false>), dim3(B_, 64), dim3(256), 0, stream,
                     outsb, pwin, pgin, pbin, pa, nullptr, nullptr, ODIM, 512);
  hipLaunchKernelGGL((k_conv<true, false>), dim3(B_, 64), dim3(256), 0, stream,
                     pa, pwmid, pgmid, pbmid, pb, nullptr, nullptr, 512, 512);
  hipLaunchKernelGGL((k_conv<true, false>), dim3(B_, 64), dim3(256), 0, stream,
                     pb, pwmid + (size_t)512 * 512 * 5, pgmid + 512, pbmid + 512,
                     pa, nullptr, nullptr, 512, 512);
  hipLaunchKernelGGL((k_conv<true, false>), dim3(B_, 64), dim3(256), 0, stream,
                     pa, pwmid + (size_t)2 * 512 * 512 * 5, pgmid + 1024, pbmid + 1024,
                     pb, nullptr, nullptr, 512, 512);
  hipLaunchKernelGGL((k_conv<false, true>), dim3(B_, 10), dim3(256), 0, stream,
                     pb, pwout, pgout, pbout, nullptr, outsb, out0, 512, ODIM);
}

// Round 4
// 11305.270 us; speedup vs baseline: 8.6309x; 8.6309x over previous
//
#include <hip/hip_runtime.h>
#include <cstdint>
#include <cstddef>

// Problem constants
constexpr int B_ = 16, T_ = 200, L_ = 250;
constexpr int IDIM = 512, ODIM = 80, DUNITS = 1024;
constexpr int ADIM = 128, ACH = 32, AK = 31;
constexpr int PRE = 256;
constexpr int TPAD = 208;   // T padded to 13*16 for MFMA t-tiles

typedef _Float16 h16;
typedef _Float16 half8 __attribute__((ext_vector_type(8)));
typedef _Float16 half4 __attribute__((ext_vector_type(4)));
typedef _Float16 half2v __attribute__((ext_vector_type(2)));
typedef float f32x4 __attribute__((ext_vector_type(4)));

// ---- workspace byte offsets (16B-aligned) ----
constexpr size_t OFF_PE    = 0;         // pe_h   [16][128][208] f16 (pad t>=200 zero)
constexpr size_t OFF_H0H   = 851968;    // h0h    [2][16][1024] f16
constexpr size_t OFF_Z1H   = 917504;    // z1h    [2][16][1024] f16
constexpr size_t OFF_ATTC  = 983040;    // attc_h [16][512] f16
constexpr size_t OFF_C0    = 999424;    // c0     [16][1024] f32
constexpr size_t OFF_C1    = 1064960;   // c1     [16][1024] f32
constexpr size_t ZERO_BYTES= 1130496;   // zero span [0, here)
constexpr size_t OFF_ATTW  = 1130496;   // attw   [2][16][200] f32 ping-pong
constexpr size_t OFF_MB    = 1156096;   // Mb     [8][64][8] f16
constexpr size_t OFF_WDH   = 1164288;   // Wdh    [1024][128] f16
constexpr size_t OFF_PREN  = 1426432;   // pren_h [250][16][256] f16
constexpr size_t OFF_HSH   = 3474432;   // hs_h   [16][200][512] f16
constexpr size_t OFF_W0H   = 6751232;   // W0h    [4096][1792] f16 (rows u*4+g)
constexpr size_t OFF_W1H   = 21431296;  // W1h    [4096][2048] f16 (rows u*4+g)
constexpr size_t OFF_Z1ALL = 38208512;  // z1all  [250][16][1024] f32
constexpr size_t OFF_OUTS  = 54592512;  // outs   [16][80][250] f32
constexpr size_t OFF_PA    = 55872512;  // postnet ping [16][512][250] f32
constexpr size_t OFF_PB    = 64064512;  // postnet pong

__device__ __forceinline__ float fsig(float x) {
  x = fminf(fmaxf(x, -30.f), 30.f);
  return __builtin_amdgcn_rcpf(1.f + __expf(-x));
}
__device__ __forceinline__ float ftanh(float x) {
  x = fminf(fmaxf(x, -15.f), 15.f);
  const float e = __expf(2.f * x);
  return (e - 1.f) * __builtin_amdgcn_rcpf(e + 1.f);
}
__device__ __forceinline__ f32x4 mfma16(half8 a, half8 b, f32x4 c) {
  return __builtin_amdgcn_mfma_f32_16x16x32_f16(a, b, c, 0, 0, 0);
}

// ---------------- prep kernels ----------------

__global__ void k_zero(float4* __restrict__ p, int n4) {
  const int i = blockIdx.x * blockDim.x + threadIdx.x;
  if (i < n4) p[i] = make_float4(0.f, 0.f, 0.f, 0.f);
}

__global__ void k_attw0(const int* __restrict__ hlens, float* __restrict__ attw) {
  const int b = blockIdx.x;
  const int hl = hlens[b];
  const float inv = 1.f / (float)hl;
  for (int t = threadIdx.x; t < T_; t += blockDim.x)
    attw[b * T_ + t] = (t < hl) ? inv : 0.f;
}

__global__ void __launch_bounds__(128) k_preenc(const float* __restrict__ hs,
    const float* __restrict__ W_enc, const float* __restrict__ b_enc,
    h16* __restrict__ pe_h) {
  const int bt = blockIdx.x, b = bt / T_, tt = bt % T_;
  __shared__ float s[IDIM];
  for (int i = threadIdx.x; i < IDIM; i += 128) s[i] = hs[(size_t)bt * IDIM + i];
  __syncthreads();
  const int a = threadIdx.x;
  float acc = b_enc[a];
#pragma unroll 4
  for (int d = 0; d < IDIM; ++d) acc += s[d] * W_enc[d * ADIM + a];
  pe_h[((size_t)b * ADIM + a) * TPAD + tt] = (h16)acc;
}

// Mb: M[k][a] = sum_c lconv[c][k] W_att[c][a], packed in MFMA B-frag order
__global__ void k_precMb(const float* __restrict__ lconv, const float* __restrict__ W_att,
                         h16* __restrict__ Mb) {
  const int at = blockIdx.x, lane = threadIdx.x;   // 8 blocks x 64 threads
  const int a = at * 16 + (lane & 15);
  const int k0 = (lane >> 4) * 8;
  half8 o;
#pragma unroll
  for (int j = 0; j < 8; ++j) {
    const int k = k0 + j;
    float v = 0.f;
    if (k < AK)
      for (int c = 0; c < ACH; ++c) v += lconv[c * AK + k] * W_att[c * ADIM + a];
    o[j] = (h16)v;
  }
  *(half8*)(Mb + (size_t)(at * 64 + lane) * 8) = o;
}

__global__ void k_cvt_w0(const float* __restrict__ Wih0, const float* __restrict__ Whh0,
                         h16* __restrict__ W0h) {
  const int rr = blockIdx.x;
  const int u = rr >> 2, g = rr & 3;
  const int orig = g * 1024 + u;
  const float* ih = Wih0 + (size_t)orig * 768;
  const float* hh = Whh0 + (size_t)orig * 1024;
  h16* out = W0h + (size_t)rr * 1792;
  for (int k = threadIdx.x; k < 1792; k += 256)
    out[k] = (h16)(k < 768 ? ih[k] : hh[k - 768]);
}

__global__ void k_cvt_w1(const float* __restrict__ Wih1, const float* __restrict__ Whh1,
                         h16* __restrict__ W1h) {
  const int rr = blockIdx.x;
  const int u = rr >> 2, g = rr & 3;
  const int orig = g * 1024 + u;
  const float* ih = Wih1 + (size_t)orig * 1024;
  const float* hh = Whh1 + (size_t)orig * 1024;
  h16* out = W1h + (size_t)rr * 2048;
  for (int k = threadIdx.x; k < 2048; k += 256)
    out[k] = (h16)(k < 1024 ? ih[k] : hh[k - 1024]);
}

__global__ void k_cvt_f32f16(const float* __restrict__ src, h16* __restrict__ dst) {
  const size_t i = ((size_t)blockIdx.x * 256 + threadIdx.x) * 4;
  const float4 v = *(const float4*)(src + i);
  half4 o; o[0] = (h16)v.x; o[1] = (h16)v.y; o[2] = (h16)v.z; o[3] = (h16)v.w;
  *(half4*)(dst + i) = o;
}

__global__ void k_prenet1(const float* __restrict__ ys, const float* __restrict__ W1,
                          float* __restrict__ h1) {
  const int bl = blockIdx.x, b = bl / L_, l = bl % L_;
  __shared__ float s[ODIM];
  if (threadIdx.x < ODIM)
    s[threadIdx.x] = (l == 0) ? 0.f : ys[((size_t)b * L_ + l - 1) * ODIM + threadIdx.x];
  __syncthreads();
  const int p = threadIdx.x;
  float acc = 0.f;
#pragma unroll 4
  for (int o = 0; o < ODIM; ++o) acc += s[o] * W1[o * PRE + p];
  h1[(size_t)bl * PRE + p] = fmaxf(acc, 0.f);
}

__global__ void k_prenet2h(const float* __restrict__ h1, const float* __restrict__ W2,
                           h16* __restrict__ pren_h) {
  const int bl = blockIdx.x, b = bl / L_, ll = bl % L_;
  __shared__ float s[PRE];
  s[threadIdx.x] = h1[(size_t)bl * PRE + threadIdx.x];
  __syncthreads();
  const int p = threadIdx.x;
  float acc = 0.f;
#pragma unroll 4
  for (int o = 0; o < PRE; ++o) acc += s[o] * W2[o * PRE + p];
  pren_h[((size_t)ll * B_ + b) * PRE + p] = (h16)fmaxf(acc, 0.f);
}

// ---------------- attention (device body; one block = one batch b) ----------------

struct AttP {
  const h16 *pe_h, *Mb, *Wdh, *hs_h;
  const float *gvw;
  const int *hlens;
  const h16 *z0;           // [16][1024] f16
  const float *attw_in;    // [16][200]
  float *attw_out;         // [16][200]
  h16 *attc;               // [16][512]
};

__device__ void att_dev(const AttP P, const int b) {
  __shared__ float s_aw[240];
  __shared__ float s_dp[ADIM];
  __shared__ float s_gv[ADIM];
  __shared__ float s_ew[256];
  __shared__ float s_wt[208];
  __shared__ float s_dpp[4][ADIM];
  __shared__ h16  s_z0h[DUNITS];
  __shared__ float s_r8[8];
  __shared__ float s_bc[2];
  const int tid = threadIdx.x;
  const int lane = tid & 63, wave = tid >> 6;
  const int l15 = lane & 15;
  const int hl = P.hlens[b];
  if (tid < 240) {
    const int tt = tid - (AK / 2);
    s_aw[tid] = (tt >= 0 && tt < T_) ? P.attw_in[b * T_ + tt] : 0.f;
  }
  if (tid < 128) *(half8*)(s_z0h + tid * 8) =
      *(const half8*)(P.z0 + b * DUNITS + tid * 8);
  if (tid < ADIM) s_gv[tid] = P.gvw[tid];
  __syncthreads();
  // ---- dp = z0 @ W_dec (f16 weights, f32 accum) ----
  {
    const int a0 = (tid & 63) * 2, kq = tid >> 6;
    float d0 = 0.f, d1 = 0.f;
    const h16* wp = P.Wdh + (size_t)(kq * 256) * ADIM + a0;
#pragma unroll 8
    for (int k = 0; k < 256; ++k) {
      const float z = (float)s_z0h[kq * 256 + k];
      const half2v wv = *(const half2v*)(wp + (size_t)k * ADIM);
      d0 += z * (float)wv[0]; d1 += z * (float)wv[1];
    }
    s_dpp[kq][a0] = d0; s_dpp[kq][a0 + 1] = d1;
  }
  __syncthreads();
  if (tid < ADIM) s_dp[tid] = s_dpp[0][tid] + s_dpp[1][tid] + s_dpp[2][tid] + s_dpp[3][tid];
  __syncthreads();
  // ---- scores: conv via MFMA + fused tanh-dot ----
  half8 bfrag[8];
#pragma unroll
  for (int at = 0; at < 8; ++at)
    bfrag[at] = *(const half8*)(P.Mb + (size_t)(at * 64 + lane) * 8);
#pragma unroll
  for (int mi = 0; mi < 4; ++mi) {
    const int mt = wave + mi * 4;
    if (mt <= 12) {
      half8 af;
#pragma unroll
      for (int j = 0; j < 8; ++j) af[j] = (h16)s_aw[mt * 16 + l15 + (lane >> 4) * 8 + j];
      const int t0 = mt * 16 + 4 * (lane >> 4);
      float e0 = 0.f, e1 = 0.f, e2 = 0.f, e3 = 0.f;
#pragma unroll
      for (int at = 0; at < 8; ++at) {
        f32x4 z4 = {0.f, 0.f, 0.f, 0.f};
        const f32x4 cv = mfma16(af, bfrag[at], z4);
        const int a = at * 16 + l15;
        const half4 pe4 = *(const half4*)(P.pe_h + ((size_t)b * ADIM + a) * TPAD + t0);
        const float g = s_gv[a], d = s_dp[a];
        e0 += g * ftanh(cv[0] + (float)pe4[0] + d);
        e1 += g * ftanh(cv[1] + (float)pe4[1] + d);
        e2 += g * ftanh(cv[2] + (float)pe4[2] + d);
        e3 += g * ftanh(cv[3] + (float)pe4[3] + d);
      }
#pragma unroll
      for (int o = 1; o < 16; o <<= 1) {
        e0 += __shfl_xor(e0, o); e1 += __shfl_xor(e1, o);
        e2 += __shfl_xor(e2, o); e3 += __shfl_xor(e3, o);
      }
      if (l15 == 0) {
        s_ew[t0 + 0] = e0; s_ew[t0 + 1] = e1; s_ew[t0 + 2] = e2; s_ew[t0 + 3] = e3;
      }
    }
  }
  __syncthreads();
  // ---- softmax over t (scale 2.0; gvec_b cancels) ----
  const float val = (tid < hl) ? 2.f * s_ew[tid] : -3.0e38f;
  float m = val;
#pragma unroll
  for (int o = 32; o > 0; o >>= 1) m = fmaxf(m, __shfl_xor(m, o));
  if ((tid & 63) == 0) s_r8[tid >> 6] = m;
  __syncthreads();
  if (tid == 0) s_bc[0] = fmaxf(fmaxf(s_r8[0], s_r8[1]), fmaxf(s_r8[2], s_r8[3]));
  __syncthreads();
  const float p = (tid < hl) ? __expf(val - s_bc[0]) : 0.f;
  float ssum = p;
#pragma unroll
  for (int o = 32; o > 0; o >>= 1) ssum += __shfl_xor(ssum, o);
  if ((tid & 63) == 0) s_r8[4 + (tid >> 6)] = ssum;
  __syncthreads();
  if (tid == 0) s_bc[1] = __builtin_amdgcn_rcpf(s_r8[4] + s_r8[5] + s_r8[6] + s_r8[7]);
  __syncthreads();
  if (tid < T_) {
    const float w = p * s_bc[1];
    s_wt[tid] = w;
    P.attw_out[b * T_ + tid] = w;
  }
  __syncthreads();
  // ---- context ----
  const h16* hsb = P.hs_h + (size_t)b * T_ * IDIM;
  float cx0 = 0.f, cx1 = 0.f;
#pragma unroll 4
  for (int tt = 0; tt < hl; ++tt) {
    const float w = s_wt[tt];
    const half2v hv = *(const half2v*)(hsb + (size_t)tt * IDIM + 2 * tid);
    cx0 += w * (float)hv[0];
    cx1 += w * (float)hv[1];
  }
  half2v o2; o2[0] = (h16)cx0; o2[1] = (h16)cx1;
  *(half2v*)(P.attc + b * IDIM + 2 * tid) = o2;
}

__global__ void __launch_bounds__(256) k_att(const AttP P) { att_dev(P, blockIdx.x); }

// ---------------- per-step kernels (sync = launch boundaries, NO spins) ----------------

// lstm0: 256 blocks, block = 16 gate rows (4 units x 4 gates), K=1792 over 4 waves
__global__ void __launch_bounds__(256) k_step1(
    const h16* __restrict__ W0h, const h16* __restrict__ attc,
    const h16* __restrict__ pren_t, const h16* __restrict__ h_in,
    h16* __restrict__ h_out, float* __restrict__ c0, const float* __restrict__ b0) {
  __shared__ float s_red[4][64][5];
  __shared__ float s_g[16][20];
  const int blk = blockIdx.x, tid = threadIdx.x;
  const int lane = tid & 63, wave = tid >> 6;
  const int nloc = lane & 15, kl8 = (lane >> 4) * 8;
  const h16* wrow = W0h + ((size_t)(blk * 16 + nloc)) * 1792 + wave * 448 + kl8;
  half8 wreg[14];
#pragma unroll
  for (int c = 0; c < 14; ++c) wreg[c] = *(const half8*)(wrow + c * 32);
  f32x4 acc = {0.f, 0.f, 0.f, 0.f};
#pragma unroll
  for (int c = 0; c < 14; ++c) {
    const int kg = wave * 448 + c * 32;
    const h16* ap;
    if (kg < 512)      ap = attc + nloc * IDIM + kg + kl8;
    else if (kg < 768) ap = pren_t + nloc * PRE + (kg - 512) + kl8;
    else               ap = h_in + nloc * DUNITS + (kg - 768) + kl8;
    acc = mfma16(*(const half8*)ap, wreg[c], acc);
  }
#pragma unroll
  for (int r = 0; r < 4; ++r) s_red[wave][lane][r] = acc[r];
  __syncthreads();
  {
    const int l = tid & 63, r = tid >> 6;
    const float v = s_red[0][l][r] + s_red[1][l][r] + s_red[2][l][r] + s_red[3][l][r];
    s_g[l & 15][4 * (l >> 4) + r] = v;
  }
  __syncthreads();
  if (tid < 64) {
    const int ul = tid >> 4, b = tid & 15;
    const int u = blk * 4 + ul;
    const float xi = s_g[ul * 4 + 0][b] + b0[u];
    const float xf = s_g[ul * 4 + 1][b] + b0[1024 + u];
    const float xg = s_g[ul * 4 + 2][b] + b0[2048 + u];
    const float xo = s_g[ul * 4 + 3][b] + b0[3072 + u];
    const int idx = b * DUNITS + u;
    const float cn = fsig(xf) * c0[idx] + fsig(xi) * ftanh(xg);
    c0[idx] = cn;
    h_out[idx] = (h16)(fsig(xo) * ftanh(cn));
  }
}

// step2: blocks 0-15 att(t+1); blocks 16-271 lstm1(t)
__global__ void __launch_bounds__(256) k_step2(
    const h16* __restrict__ W1h, const h16* __restrict__ z0,
    const h16* __restrict__ z1_in, h16* __restrict__ z1_out,
    float* __restrict__ c1, const float* __restrict__ b1,
    float* __restrict__ z1all_t, const AttP P, const int do_att) {
  if (blockIdx.x < 16) {
    if (do_att) att_dev(P, blockIdx.x);
    return;
  }
  __shared__ float s_red[4][64][5];
  __shared__ float s_g[16][20];
  const int blk = blockIdx.x - 16, tid = threadIdx.x;
  const int lane = tid & 63, wave = tid >> 6;
  const int nloc = lane & 15, kl8 = (lane >> 4) * 8;
  const h16* wrow = W1h + ((size_t)(blk * 16 + nloc)) * 2048 + wave * 512 + kl8;
  half8 wreg[16];
#pragma unroll
  for (int c = 0; c < 16; ++c) wreg[c] = *(const half8*)(wrow + c * 32);
  f32x4 acc = {0.f, 0.f, 0.f, 0.f};
#pragma unroll
  for (int c = 0; c < 16; ++c) {
    const int kg = wave * 512 + c * 32;
    const h16* ap = (kg < 1024) ? (z0 + nloc * DUNITS + kg + kl8)
                                : (z1_in + nloc * DUNITS + (kg - 1024) + kl8);
    acc = mfma16(*(const half8*)ap, wreg[c], acc);
  }
#pragma unroll
  for (int r = 0; r < 4; ++r) s_red[wave][lane][r] = acc[r];
  __syncthreads();
  {
    const int l = tid & 63, r = tid >> 6;
    const float v = s_red[0][l][r] + s_red[1][l][r] + s_red[2][l][r] + s_red[3][l][r];
    s_g[l & 15][4 * (l >> 4) + r] = v;
  }
  __syncthreads();
  if (tid < 64) {
    const int ul = tid >> 4, b = tid & 15;
    const int u = blk * 4 + ul;
    const float xi = s_g[ul * 4 + 0][b] + b1[u];
    const float xf = s_g[ul * 4 + 1][b] + b1[1024 + u];
    const float xg = s_g[ul * 4 + 2][b] + b1[2048 + u];
    const float xo = s_g[ul * 4 + 3][b] + b1[3072 + u];
    const int idx = b * DUNITS + u;
    const float cn = fsig(xf) * c1[idx] + fsig(xi) * ftanh(xg);
    c1[idx] = cn;
    const float hn = fsig(xo) * ftanh(cn);
    z1_out[idx] = (h16)hn;
    z1all_t[idx] = hn;
  }
}

// ---------------- output heads + postnet ----------------

__global__ void __launch_bounds__(128) k_heads(const float* __restrict__ z1_all,
    const float* __restrict__ feat_W, const float* __restrict__ prob_W,
    const float* __restrict__ prob_b, float* __restrict__ out1,
    float* __restrict__ probs, float* __restrict__ outs_bct) {
  const int bl = blockIdx.x, b = bl / L_, l = bl % L_;
  __shared__ float s_z[DUNITS];
  const float* z = z1_all + ((size_t)l * B_ + b) * DUNITS;
  for (int i = threadIdx.x; i < DUNITS; i += 128) s_z[i] = z[i];
  __syncthreads();
  const int co = threadIdx.x;
  if (co < ODIM) {
    float acc = 0.f;
#pragma unroll 4
    for (int d = 0; d < DUNITS; ++d) acc += s_z[d] * feat_W[d * ODIM + co];
    out1[((size_t)b * L_ + l) * ODIM + co] = acc;
    outs_bct[((size_t)b * ODIM + co) * L_ + l] = acc;
  } else if (co == 96) {
    float acc = prob_b[0];
#pragma unroll 4
    for (int d = 0; d < DUNITS; ++d) acc += s_z[d] * prob_W[d];
    probs[(size_t)b * L_ + l] = acc;
  }
}

template <bool TANH, bool FINAL>
__global__ void __launch_bounds__(256) k_conv(const float* __restrict__ x,
    const float* __restrict__ w, const float* __restrict__ gamma,
    const float* __restrict__ beta, float* __restrict__ y,
    const float* __restrict__ res, float* __restrict__ out0,
    const int Cin, const int Cout) {
  const int b = blockIdx.x;
  const int co0 = blockIdx.y * 8;
  const int tid = threadIdx.x;
  const int l = tid & 127;
  const int cg = tid >> 7;
  __shared__ float s_x[8][260];
  __shared__ float s_w[8][8][5];
  float acc[4][2] = {{0.f, 0.f}, {0.f, 0.f}, {0.f, 0.f}, {0.f, 0.f}};
  for (int ci0 = 0; ci0 < Cin; ci0 += 8) {
    __syncthreads();
    for (int i = tid; i < 8 * 260; i += 256) {
      const int ci = i / 260, col = i % 260;
      const int ll = col - 2;
      s_x[ci][col] = (ll >= 0 && ll < L_) ? x[((size_t)b * Cin + ci0 + ci) * L_ + ll] : 0.f;
    }
    for (int i = tid; i < 8 * 8 * 5; i += 256) {
      const int ci = i / 40, rem = i % 40, cl = rem / 5, k = rem % 5;
      s_w[ci][cl][k] = w[((size_t)(co0 + cl) * Cin + ci0 + ci) * 5 + k];
    }
    __syncthreads();
#pragma unroll 2
    for (int ci = 0; ci < 8; ++ci) {
      float xv0[5], xv1[5];
#pragma unroll
      for (int k = 0; k < 5; ++k) { xv0[k] = s_x[ci][l + k]; xv1[k] = s_x[ci][l + 128 + k]; }
#pragma unroll
      for (int j = 0; j < 4; ++j) {
        const int cl = cg * 4 + j;
#pragma unroll
        for (int k = 0; k < 5; ++k) {
          const float ww = s_w[ci][cl][k];
          acc[j][0] += ww * xv0[k];
          acc[j][1] += ww * xv1[k];
        }
      }
    }
  }
#pragma unroll
  for (int j = 0; j < 4; ++j) {
    const int co = co0 + cg * 4 + j;
    const float gm = gamma[co], bt = beta[co];
#pragma unroll
    for (int h = 0; h < 2; ++h) {
      const int ll = l + h * 128;
      if (ll < L_) {
        float v = gm * acc[j][h] + bt;
        if (TANH) v = ftanh(v);
        if (FINAL) out0[((size_t)b * L_ + ll) * ODIM + co] =
                       res[((size_t)b * ODIM + co) * L_ + ll] + v;
        else y[((size_t)b * Cout + co) * L_ + ll] = v;
      }
    }
  }
}

// ---------------- launch ----------------

extern "C" void kernel_launch(void* const* d_in, const int* in_sizes, int n_in,
                              void* d_out, int out_size, void* d_ws, size_t ws_size,
                              hipStream_t stream) {
  const float* hs    = (const float*)d_in[0];
  const int*   hlens = (const int*)d_in[1];
  const float* ys    = (const float*)d_in[2];
  const float* W_enc = (const float*)d_in[3];
  const float* b_enc = (const float*)d_in[4];
  const float* W_dec = (const float*)d_in[5];
  const float* W_att = (const float*)d_in[6];
  const float* lconv = (const float*)d_in[7];
  const float* gvw   = (const float*)d_in[8];
  const float* pW1   = (const float*)d_in[10];
  const float* pW2   = (const float*)d_in[11];
  const float* Wih0  = (const float*)d_in[12];
  const float* Whh0  = (const float*)d_in[13];
  const float* b0    = (const float*)d_in[14];
  const float* Wih1  = (const float*)d_in[15];
  const float* Whh1  = (const float*)d_in[16];
  const float* b1    = (const float*)d_in[17];
  const float* featW = (const float*)d_in[18];
  const float* probW = (const float*)d_in[19];
  const float* probB = (const float*)d_in[20];
  const float* pwin  = (const float*)d_in[21];
  const float* pgin  = (const float*)d_in[22];
  const float* pbin  = (const float*)d_in[23];
  const float* pwmid = (const float*)d_in[24];
  const float* pgmid = (const float*)d_in[25];
  const float* pbmid = (const float*)d_in[26];
  const float* pwout = (const float*)d_in[27];
  const float* pgout = (const float*)d_in[28];
  const float* pbout = (const float*)d_in[29];

  char* ws = (char*)d_ws;
  h16*   pe_h   = (h16*)(ws + OFF_PE);
  h16*   h0h    = (h16*)(ws + OFF_H0H);
  h16*   z1h    = (h16*)(ws + OFF_Z1H);
  h16*   attc_h = (h16*)(ws + OFF_ATTC);
  float* c0     = (float*)(ws + OFF_C0);
  float* c1     = (float*)(ws + OFF_C1);
  float* attw   = (float*)(ws + OFF_ATTW);
  h16*   Mb     = (h16*)(ws + OFF_MB);
  h16*   Wdh    = (h16*)(ws + OFF_WDH);
  h16*   pren_h = (h16*)(ws + OFF_PREN);
  h16*   hs_h   = (h16*)(ws + OFF_HSH);
  h16*   W0h    = (h16*)(ws + OFF_W0H);
  h16*   W1h    = (h16*)(ws + OFF_W1H);
  float* z1all  = (float*)(ws + OFF_Z1ALL);
  float* outsb  = (float*)(ws + OFF_OUTS);
  float* pa     = (float*)(ws + OFF_PA);
  float* pb     = (float*)(ws + OFF_PB);

  float* out0 = (float*)d_out;
  float* out1 = out0 + (size_t)B_ * L_ * ODIM;
  float* out2 = out1 + (size_t)B_ * L_ * ODIM;

  // prep
  hipLaunchKernelGGL(k_zero, dim3((ZERO_BYTES / 16 + 255) / 256), dim3(256), 0, stream,
                     (float4*)ws, (int)(ZERO_BYTES / 16));
  hipLaunchKernelGGL(k_attw0, dim3(B_), dim3(256), 0, stream, hlens, attw);
  hipLaunchKernelGGL(k_preenc, dim3(B_ * T_), dim3(128), 0, stream, hs, W_enc, b_enc, pe_h);
  hipLaunchKernelGGL(k_precMb, dim3(8), dim3(64), 0, stream, lconv, W_att, Mb);
  hipLaunchKernelGGL(k_cvt_w0, dim3(4096), dim3(256), 0, stream, Wih0, Whh0, W0h);
  hipLaunchKernelGGL(k_cvt_w1, dim3(4096), dim3(256), 0, stream, Wih1, Whh1, W1h);
  hipLaunchKernelGGL(k_cvt_f32f16, dim3(128), dim3(256), 0, stream, W_dec, Wdh);
  hipLaunchKernelGGL(k_cvt_f32f16, dim3(1600), dim3(256), 0, stream, hs, hs_h);
  hipLaunchKernelGGL(k_prenet1, dim3(B_ * L_), dim3(PRE), 0, stream, ys, pW1, pa);
  hipLaunchKernelGGL(k_prenet2h, dim3(B_ * L_), dim3(PRE), 0, stream, pa, pW2, pren_h);

  constexpr int BD = B_ * DUNITS;
  constexpr int BT = B_ * T_;

  // att(0): z0 = zeros (h0h buf0), attw buf0 -> buf1
  {
    const AttP P{pe_h, Mb, Wdh, hs_h, gvw, hlens, h0h, attw, attw + BT, attc_h};
    hipLaunchKernelGGL(k_att, dim3(B_), dim3(256), 0, stream, P);
  }

  // scan: 2 launches per step, dependencies carried by launch order only
  for (int t = 0; t < L_; ++t) {
    const int pi = t & 1, po = 1 - pi;
    hipLaunchKernelGGL(k_step1, dim3(256), dim3(256), 0, stream,
                       W0h, attc_h, pren_h + (size_t)t * (B_ * PRE),
                       h0h + (size_t)pi * BD, h0h + (size_t)po * BD, c0, b0);
    const AttP P{pe_h, Mb, Wdh, hs_h, gvw, hlens,
                 h0h + (size_t)po * BD, attw + (size_t)po * BT, attw + (size_t)pi * BT,
                 attc_h};
    hipLaunchKernelGGL(k_step2, dim3(272), dim3(256), 0, stream,
                       W1h, h0h + (size_t)po * BD,
                       z1h + (size_t)pi * BD, z1h + (size_t)po * BD,
                       c1, b1, z1all + (size_t)t * BD, P, (t + 1 < L_) ? 1 : 0);
  }

  hipLaunchKernelGGL(k_heads, dim3(B_ * L_), dim3(128), 0, stream,
                     z1all, featW, probW, probB, out1, out2, outsb);

  hipLaunchKernelGGL((k_conv<true, false>), dim3(B_, 64), dim3(256), 0, stream,
                     outsb, pwin, pgin, pbin, pa, nullptr, nullptr, ODIM, 512);
  hipLaunchKernelGGL((k_conv<true, false>), dim3(B_, 64), dim3(256), 0, stream,
                     pa, pwmid, pgmid, pbmid, pb, nullptr, nullptr, 512, 512);
  hipLaunchKernelGGL((k_conv<true, false>), dim3(B_, 64), dim3(256), 0, stream,
                     pb, pwmid + (size_t)512 * 512 * 5, pgmid + 512, pbmid + 512,
                     pa, nullptr, nullptr, 512, 512);
  hipLaunchKernelGGL((k_conv<true, false>), dim3(B_, 64), dim3(256), 0, stream,
                     pa, pwmid + (size_t)2 * 512 * 512 * 5, pgmid + 1024, pbmid + 1024,
                     pb, nullptr, nullptr, 512, 512);
  hipLaunchKernelGGL((k_conv<false, true>), dim3(B_, 10), dim3(256), 0, stream,
                     pb, pwout, pgout, pbout, nullptr, outsb, out0, 512, ODIM);
}

// Round 5
// 11256.653 us; speedup vs baseline: 8.6682x; 1.0043x over previous
//
#include <hip/hip_runtime.h>
#include <cstdint>
#include <cstddef>

// Problem constants
constexpr int B_ = 16, T_ = 200, L_ = 250;
constexpr int IDIM = 512, ODIM = 80, DUNITS = 1024;
constexpr int ADIM = 128, ACH = 32, AK = 31;
constexpr int PRE = 256;
constexpr int TPAD = 208;   // T padded to 13*16 for MFMA t-tiles

typedef _Float16 h16;
typedef _Float16 half8 __attribute__((ext_vector_type(8)));
typedef _Float16 half4 __attribute__((ext_vector_type(4)));
typedef _Float16 half2v __attribute__((ext_vector_type(2)));
typedef float f32x4 __attribute__((ext_vector_type(4)));

// ---- workspace byte offsets (16B-aligned) ----
constexpr size_t OFF_PE    = 0;         // pe_h   [16][128][208] f16 (pad t>=200 zero)
constexpr size_t OFF_H0H   = 851968;    // h0h    [2][16][1024] f16
constexpr size_t OFF_Z1H   = 917504;    // z1h    [2][16][1024] f16
constexpr size_t OFF_ATTC  = 983040;    // attc_h [16][512] f16
constexpr size_t OFF_C0    = 999424;    // c0     [16][1024] f32
constexpr size_t OFF_C1    = 1064960;   // c1     [16][1024] f32
constexpr size_t OFF_GH0   = 1130496;   // gh0    [16][4096] f32 (Whh0@z0 partial)
constexpr size_t OFF_GZ1   = 1392640;   // gz1    [16][4096] f32 (Whh1@z1 partial)
constexpr size_t ZERO_BYTES= 1654784;   // zero span [0, here)
constexpr size_t OFF_ATTW  = 1654784;   // attw   [2][16][200] f32 ping-pong
constexpr size_t OFF_MB    = 1680384;   // Mb     [8][64][8] f16
constexpr size_t OFF_WDH   = 1688576;   // Wdh    [1024][128] f16
constexpr size_t OFF_PREN  = 1950720;   // pren_h [250][16][256] f16
constexpr size_t OFF_HSH   = 3998720;   // hs_h   [16][200][512] f16
constexpr size_t OFF_W0AH  = 7275520;   // W0ah   [4096][768]  f16 (rows u*4+g)
constexpr size_t OFF_WHH0  = 13566976;  // Whh0h  [4096][1024] f16
constexpr size_t OFF_WI1   = 21955584;  // Wz01h  [4096][1024] f16 (Wih1)
constexpr size_t OFF_WHH1  = 30344192;  // Whh1h  [4096][1024] f16
constexpr size_t OFF_Z1ALL = 38732800;  // z1all  [250][16][1024] f32
constexpr size_t OFF_OUTS  = 55116800;  // outs   [16][80][250] f32
constexpr size_t OFF_PA    = 56396800;  // postnet ping [16][512][250] f32
constexpr size_t OFF_PB    = 64588800;  // postnet pong

__device__ __forceinline__ float fsig(float x) {
  x = fminf(fmaxf(x, -30.f), 30.f);
  return __builtin_amdgcn_rcpf(1.f + __expf(-x));
}
__device__ __forceinline__ float ftanh(float x) {
  x = fminf(fmaxf(x, -15.f), 15.f);
  const float e = __expf(2.f * x);
  return (e - 1.f) * __builtin_amdgcn_rcpf(e + 1.f);
}
__device__ __forceinline__ f32x4 mfma16(half8 a, half8 b, f32x4 c) {
  return __builtin_amdgcn_mfma_f32_16x16x32_f16(a, b, c, 0, 0, 0);
}

// ---------------- prep kernels ----------------

__global__ void k_zero(float4* __restrict__ p, int n4) {
  const int i = blockIdx.x * blockDim.x + threadIdx.x;
  if (i < n4) p[i] = make_float4(0.f, 0.f, 0.f, 0.f);
}

__global__ void k_attw0(const int* __restrict__ hlens, float* __restrict__ attw) {
  const int b = blockIdx.x;
  const int hl = hlens[b];
  const float inv = 1.f / (float)hl;
  for (int t = threadIdx.x; t < T_; t += blockDim.x)
    attw[b * T_ + t] = (t < hl) ? inv : 0.f;
}

__global__ void __launch_bounds__(128) k_preenc(const float* __restrict__ hs,
    const float* __restrict__ W_enc, const float* __restrict__ b_enc,
    h16* __restrict__ pe_h) {
  const int bt = blockIdx.x, b = bt / T_, tt = bt % T_;
  __shared__ float s[IDIM];
  for (int i = threadIdx.x; i < IDIM; i += 128) s[i] = hs[(size_t)bt * IDIM + i];
  __syncthreads();
  const int a = threadIdx.x;
  float acc = b_enc[a];
#pragma unroll 4
  for (int d = 0; d < IDIM; ++d) acc += s[d] * W_enc[d * ADIM + a];
  pe_h[((size_t)b * ADIM + a) * TPAD + tt] = (h16)acc;
}

// Mb: M[k][a] = sum_c lconv[c][k] W_att[c][a], packed in MFMA B-frag order
__global__ void k_precMb(const float* __restrict__ lconv, const float* __restrict__ W_att,
                         h16* __restrict__ Mb) {
  const int at = blockIdx.x, lane = threadIdx.x;   // 8 blocks x 64 threads
  const int a = at * 16 + (lane & 15);
  const int k0 = (lane >> 4) * 8;
  half8 o;
#pragma unroll
  for (int j = 0; j < 8; ++j) {
    const int k = k0 + j;
    float v = 0.f;
    if (k < AK)
      for (int c = 0; c < ACH; ++c) v += lconv[c * AK + k] * W_att[c * ADIM + a];
    o[j] = (h16)v;
  }
  *(half8*)(Mb + (size_t)(at * 64 + lane) * 8) = o;
}

// generic gate-permute + f32->f16: dst row rr=u*4+g <- src row g*1024+u, K cols
__global__ void k_cvt_perm(const float* __restrict__ src, h16* __restrict__ dst,
                           const int K) {
  const int rr = blockIdx.x;
  const int u = rr >> 2, g = rr & 3;
  const float* s = src + (size_t)(g * 1024 + u) * K;
  h16* d = dst + (size_t)rr * K;
  for (int k = threadIdx.x; k < K; k += 256) d[k] = (h16)s[k];
}

__global__ void k_cvt_f32f16(const float* __restrict__ src, h16* __restrict__ dst) {
  const size_t i = ((size_t)blockIdx.x * 256 + threadIdx.x) * 4;
  const float4 v = *(const float4*)(src + i);
  half4 o; o[0] = (h16)v.x; o[1] = (h16)v.y; o[2] = (h16)v.z; o[3] = (h16)v.w;
  *(half4*)(dst + i) = o;
}

__global__ void k_prenet1(const float* __restrict__ ys, const float* __restrict__ W1,
                          float* __restrict__ h1) {
  const int bl = blockIdx.x, b = bl / L_, l = bl % L_;
  __shared__ float s[ODIM];
  if (threadIdx.x < ODIM)
    s[threadIdx.x] = (l == 0) ? 0.f : ys[((size_t)b * L_ + l - 1) * ODIM + threadIdx.x];
  __syncthreads();
  const int p = threadIdx.x;
  float acc = 0.f;
#pragma unroll 4
  for (int o = 0; o < ODIM; ++o) acc += s[o] * W1[o * PRE + p];
  h1[(size_t)bl * PRE + p] = fmaxf(acc, 0.f);
}

__global__ void k_prenet2h(const float* __restrict__ h1, const float* __restrict__ W2,
                           h16* __restrict__ pren_h) {
  const int bl = blockIdx.x, b = bl / L_, ll = bl % L_;
  __shared__ float s[PRE];
  s[threadIdx.x] = h1[(size_t)bl * PRE + threadIdx.x];
  __syncthreads();
  const int p = threadIdx.x;
  float acc = 0.f;
#pragma unroll 4
  for (int o = 0; o < PRE; ++o) acc += s[o] * W2[o * PRE + p];
  pren_h[((size_t)ll * B_ + b) * PRE + p] = (h16)fmaxf(acc, 0.f);
}

// ---------------- attention (device body; one block = one batch b) ----------------

struct AttP {
  const h16 *pe_h, *Mb, *Wdh, *hs_h;
  const float *gvw;
  const int *hlens;
  const h16 *z0;           // [16][1024] f16
  const float *attw_in;    // [16][200]
  float *attw_out;         // [16][200]
  h16 *attc;               // [16][512]
};

__device__ void att_dev(const AttP P, const int b) {
  __shared__ float s_aw[240];
  __shared__ float s_dp[ADIM];
  __shared__ float s_gv[ADIM];
  __shared__ float s_ew[256];
  __shared__ float s_wt[208];
  __shared__ float s_par[16][ADIM];   // dp partials (8KB); reused as ctx [4][512]
  __shared__ h16  s_z0h[DUNITS];
  __shared__ float s_r8[8];
  __shared__ float s_bc[2];
  const int tid = threadIdx.x;
  const int lane = tid & 63, wave = tid >> 6;
  const int l15 = lane & 15;
  const int hl = P.hlens[b];
  if (tid < 240) {
    const int tt = tid - (AK / 2);
    s_aw[tid] = (tt >= 0 && tt < T_) ? P.attw_in[b * T_ + tt] : 0.f;
  }
  if (tid < 128) {
    *(half8*)(s_z0h + tid * 8) = *(const half8*)(P.z0 + b * DUNITS + tid * 8);
    s_gv[tid] = P.gvw[tid];
  }
  __syncthreads();
  // ---- dp = z0 @ W_dec: thread = (kq 0..15, a-oct 0..15), 64 k-iters, half8 a-loads
  {
    const int kq = tid >> 4, ao = (tid & 15) * 8;
    const h16* wp = P.Wdh + (size_t)(kq * 64) * ADIM + ao;
    float a8[8] = {0.f, 0.f, 0.f, 0.f, 0.f, 0.f, 0.f, 0.f};
#pragma unroll 4
    for (int k = 0; k < 64; ++k) {
      const float z = (float)s_z0h[kq * 64 + k];
      const half8 wv = *(const half8*)(wp + (size_t)k * ADIM);
#pragma unroll
      for (int j = 0; j < 8; ++j) a8[j] += z * (float)wv[j];
    }
#pragma unroll
    for (int j = 0; j < 8; ++j) s_par[kq][ao + j] = a8[j];
  }
  __syncthreads();
  if (tid < ADIM) {
    float s = 0.f;
#pragma unroll
    for (int q = 0; q < 16; ++q) s += s_par[q][tid];
    s_dp[tid] = s;
  }
  __syncthreads();
  // ---- scores: conv via MFMA + fused tanh-dot ----
  half8 bfrag[8];
#pragma unroll
  for (int at = 0; at < 8; ++at)
    bfrag[at] = *(const half8*)(P.Mb + (size_t)(at * 64 + lane) * 8);
#pragma unroll
  for (int mi = 0; mi < 4; ++mi) {
    const int mt = wave + mi * 4;
    if (mt <= 12) {
      half8 af;
#pragma unroll
      for (int j = 0; j < 8; ++j) af[j] = (h16)s_aw[mt * 16 + l15 + (lane >> 4) * 8 + j];
      const int t0 = mt * 16 + 4 * (lane >> 4);
      float e0 = 0.f, e1 = 0.f, e2 = 0.f, e3 = 0.f;
#pragma unroll
      for (int at = 0; at < 8; ++at) {
        f32x4 z4 = {0.f, 0.f, 0.f, 0.f};
        const f32x4 cv = mfma16(af, bfrag[at], z4);
        const int a = at * 16 + l15;
        const half4 pe4 = *(const half4*)(P.pe_h + ((size_t)b * ADIM + a) * TPAD + t0);
        const float g = s_gv[a], d = s_dp[a];
        e0 += g * ftanh(cv[0] + (float)pe4[0] + d);
        e1 += g * ftanh(cv[1] + (float)pe4[1] + d);
        e2 += g * ftanh(cv[2] + (float)pe4[2] + d);
        e3 += g * ftanh(cv[3] + (float)pe4[3] + d);
      }
#pragma unroll
      for (int o = 1; o < 16; o <<= 1) {
        e0 += __shfl_xor(e0, o); e1 += __shfl_xor(e1, o);
        e2 += __shfl_xor(e2, o); e3 += __shfl_xor(e3, o);
      }
      if (l15 == 0) {
        s_ew[t0 + 0] = e0; s_ew[t0 + 1] = e1; s_ew[t0 + 2] = e2; s_ew[t0 + 3] = e3;
      }
    }
  }
  __syncthreads();
  // ---- softmax over t (scale 2.0; gvec_b cancels) ----
  const float val = (tid < hl) ? 2.f * s_ew[tid] : -3.0e38f;
  float m = val;
#pragma unroll
  for (int o = 32; o > 0; o >>= 1) m = fmaxf(m, __shfl_xor(m, o));
  if ((tid & 63) == 0) s_r8[tid >> 6] = m;
  __syncthreads();
  if (tid == 0) s_bc[0] = fmaxf(fmaxf(s_r8[0], s_r8[1]), fmaxf(s_r8[2], s_r8[3]));
  __syncthreads();
  const float p = (tid < hl) ? __expf(val - s_bc[0]) : 0.f;
  float ssum = p;
#pragma unroll
  for (int o = 32; o > 0; o >>= 1) ssum += __shfl_xor(ssum, o);
  if ((tid & 63) == 0) s_r8[4 + (tid >> 6)] = ssum;
  __syncthreads();
  if (tid == 0) s_bc[1] = __builtin_amdgcn_rcpf(s_r8[4] + s_r8[5] + s_r8[6] + s_r8[7]);
  __syncthreads();
  if (tid < T_) {
    const float w = p * s_bc[1];
    s_wt[tid] = w;
    P.attw_out[b * T_ + tid] = w;
  }
  __syncthreads();
  // ---- context: wave = t mod 4, lane = d-oct; coalesced half8 loads ----
  float* s_ctx = &s_par[0][0];
  const h16* hsb = P.hs_h + (size_t)b * T_ * IDIM;
  {
    const int d0 = lane * 8;
    float a8[8] = {0.f, 0.f, 0.f, 0.f, 0.f, 0.f, 0.f, 0.f};
    for (int tt = wave; tt < hl; tt += 4) {
      const float wt = s_wt[tt];
      const half8 hv = *(const half8*)(hsb + (size_t)tt * IDIM + d0);
#pragma unroll
      for (int j = 0; j < 8; ++j) a8[j] += wt * (float)hv[j];
    }
#pragma unroll
    for (int j = 0; j < 8; ++j) s_ctx[wave * 512 + d0 + j] = a8[j];
  }
  __syncthreads();
  {
    const int d = tid * 2;
    const float cx0 = s_ctx[d] + s_ctx[512 + d] + s_ctx[1024 + d] + s_ctx[1536 + d];
    const float cx1 = s_ctx[d + 1] + s_ctx[512 + d + 1] + s_ctx[1024 + d + 1]
                    + s_ctx[1536 + d + 1];
    half2v o2; o2[0] = (h16)cx0; o2[1] = (h16)cx1;
    *(half2v*)(P.attc + b * IDIM + d) = o2;
  }
}

__global__ void __launch_bounds__(256) k_att(const AttP P) { att_dev(P, blockIdx.x); }

// ---------------- per-step kernels (sync = launch boundaries) ----------------

// k_step1, grid 512:
//  blocks 0-255:  gates0 = W0a@[attc;pren] (K=768) + gh0 + b0 -> z0(t), c0
//  blocks 256-511: gz1 = Whh1 @ z1(t-1)   (K=1024) partial for lstm1
__global__ void __launch_bounds__(256) k_step1(
    const h16* __restrict__ W0ah, const h16* __restrict__ Whh1h,
    const h16* __restrict__ attc, const h16* __restrict__ pren_t,
    const h16* __restrict__ z1_in, const float* __restrict__ gh0,
    float* __restrict__ gz1, h16* __restrict__ z0_out,
    float* __restrict__ c0, const float* __restrict__ b0) {
  __shared__ float s_red[4][64][5];
  __shared__ float s_g[16][20];
  const int tid = threadIdx.x;
  const int lane = tid & 63, wave = tid >> 6;
  const int nloc = lane & 15, kl8 = (lane >> 4) * 8;
  if (blockIdx.x < 256) {
    const int blk = blockIdx.x;
    const h16* wrow = W0ah + ((size_t)(blk * 16 + nloc)) * 768 + wave * 192 + kl8;
    half8 wreg[6];
#pragma unroll
    for (int c = 0; c < 6; ++c) wreg[c] = *(const half8*)(wrow + c * 32);
    f32x4 acc = {0.f, 0.f, 0.f, 0.f};
#pragma unroll
    for (int c = 0; c < 6; ++c) {
      const int kg = wave * 192 + c * 32;
      const h16* ap = (kg < 512) ? (attc + nloc * IDIM + kg + kl8)
                                 : (pren_t + nloc * PRE + (kg - 512) + kl8);
      acc = mfma16(*(const half8*)ap, wreg[c], acc);
    }
#pragma unroll
    for (int r = 0; r < 4; ++r) s_red[wave][lane][r] = acc[r];
    __syncthreads();
    {
      const int l = tid & 63, r = tid >> 6;
      float v = s_red[0][l][r] + s_red[1][l][r] + s_red[2][l][r] + s_red[3][l][r];
      v += gh0[(size_t)(4 * (l >> 4) + r) * 4096 + blk * 16 + (l & 15)];
      s_g[l & 15][4 * (l >> 4) + r] = v;
    }
    __syncthreads();
    if (tid < 64) {
      const int ul = tid >> 4, b = tid & 15;
      const int u = blk * 4 + ul;
      const float xi = s_g[ul * 4 + 0][b] + b0[u];
      const float xf = s_g[ul * 4 + 1][b] + b0[1024 + u];
      const float xg = s_g[ul * 4 + 2][b] + b0[2048 + u];
      const float xo = s_g[ul * 4 + 3][b] + b0[3072 + u];
      const int idx = b * DUNITS + u;
      const float cn = fsig(xf) * c0[idx] + fsig(xi) * ftanh(xg);
      c0[idx] = cn;
      z0_out[idx] = (h16)(fsig(xo) * ftanh(cn));
    }
  } else {
    const int blk = blockIdx.x - 256;
    const h16* wrow = Whh1h + ((size_t)(blk * 16 + nloc)) * 1024 + wave * 256 + kl8;
    half8 wreg[8];
#pragma unroll
    for (int c = 0; c < 8; ++c) wreg[c] = *(const half8*)(wrow + c * 32);
    f32x4 acc = {0.f, 0.f, 0.f, 0.f};
#pragma unroll
    for (int c = 0; c < 8; ++c) {
      const h16* ap = z1_in + nloc * DUNITS + wave * 256 + c * 32 + kl8;
      acc = mfma16(*(const half8*)ap, wreg[c], acc);
    }
#pragma unroll
    for (int r = 0; r < 4; ++r) s_red[wave][lane][r] = acc[r];
    __syncthreads();
    const int l = tid & 63, r = tid >> 6;
    const float v = s_red[0][l][r] + s_red[1][l][r] + s_red[2][l][r] + s_red[3][l][r];
    gz1[(size_t)(4 * (l >> 4) + r) * 4096 + blk * 16 + (l & 15)] = v;
  }
}

// k_step2, grid 528:
//  blocks 0-15:    att(t+1) (reads z0(t))
//  blocks 16-271:  gates1 = Wih1@z0(t) (K=1024) + gz1 + b1 -> z1(t), c1, z1all
//  blocks 272-527: gh0(t+1) = Whh0 @ z0(t) (K=1024)
__global__ void __launch_bounds__(256) k_step2(
    const h16* __restrict__ Wz01h, const h16* __restrict__ Whh0h,
    const h16* __restrict__ z0, const float* __restrict__ gz1,
    float* __restrict__ gh0, h16* __restrict__ z1_out,
    float* __restrict__ c1, const float* __restrict__ b1,
    float* __restrict__ z1all_t, const AttP P, const int do_att) {
  if (blockIdx.x < 16) {
    if (do_att) att_dev(P, blockIdx.x);
    return;
  }
  __shared__ float s_red[4][64][5];
  __shared__ float s_g[16][20];
  const bool isL = blockIdx.x < 272;
  const int blk = isL ? (blockIdx.x - 16) : (blockIdx.x - 272);
  const int tid = threadIdx.x;
  const int lane = tid & 63, wave = tid >> 6;
  const int nloc = lane & 15, kl8 = (lane >> 4) * 8;
  const h16* W = isL ? Wz01h : Whh0h;
  const h16* wrow = W + ((size_t)(blk * 16 + nloc)) * 1024 + wave * 256 + kl8;
  half8 wreg[8];
#pragma unroll
  for (int c = 0; c < 8; ++c) wreg[c] = *(const half8*)(wrow + c * 32);
  f32x4 acc = {0.f, 0.f, 0.f, 0.f};
#pragma unroll
  for (int c = 0; c < 8; ++c) {
    const h16* ap = z0 + nloc * DUNITS + wave * 256 + c * 32 + kl8;
    acc = mfma16(*(const half8*)ap, wreg[c], acc);
  }
#pragma unroll
  for (int r = 0; r < 4; ++r) s_red[wave][lane][r] = acc[r];
  __syncthreads();
  const int l = tid & 63, r = tid >> 6;
  float v = s_red[0][l][r] + s_red[1][l][r] + s_red[2][l][r] + s_red[3][l][r];
  if (!isL) {
    gh0[(size_t)(4 * (l >> 4) + r) * 4096 + blk * 16 + (l & 15)] = v;
    return;
  }
  v += gz1[(size_t)(4 * (l >> 4) + r) * 4096 + blk * 16 + (l & 15)];
  s_g[l & 15][4 * (l >> 4) + r] = v;
  __syncthreads();
  if (tid < 64) {
    const int ul = tid >> 4, b = tid & 15;
    const int u = blk * 4 + ul;
    const float xi = s_g[ul * 4 + 0][b] + b1[u];
    const float xf = s_g[ul * 4 + 1][b] + b1[1024 + u];
    const float xg = s_g[ul * 4 + 2][b] + b1[2048 + u];
    const float xo = s_g[ul * 4 + 3][b] + b1[3072 + u];
    const int idx = b * DUNITS + u;
    const float cn = fsig(xf) * c1[idx] + fsig(xi) * ftanh(xg);
    c1[idx] = cn;
    const float hn = fsig(xo) * ftanh(cn);
    z1_out[idx] = (h16)hn;
    z1all_t[idx] = hn;
  }
}

// ---------------- output heads + postnet ----------------

__global__ void __launch_bounds__(128) k_heads(const float* __restrict__ z1_all,
    const float* __restrict__ feat_W, const float* __restrict__ prob_W,
    const float* __restrict__ prob_b, float* __restrict__ out1,
    float* __restrict__ probs, float* __restrict__ outs_bct) {
  const int bl = blockIdx.x, b = bl / L_, l = bl % L_;
  __shared__ float s_z[DUNITS];
  const float* z = z1_all + ((size_t)l * B_ + b) * DUNITS;
  for (int i = threadIdx.x; i < DUNITS; i += 128) s_z[i] = z[i];
  __syncthreads();
  const int co = threadIdx.x;
  if (co < ODIM) {
    float acc = 0.f;
#pragma unroll 4
    for (int d = 0; d < DUNITS; ++d) acc += s_z[d] * feat_W[d * ODIM + co];
    out1[((size_t)b * L_ + l) * ODIM + co] = acc;
    outs_bct[((size_t)b * ODIM + co) * L_ + l] = acc;
  } else if (co == 96) {
    float acc = prob_b[0];
#pragma unroll 4
    for (int d = 0; d < DUNITS; ++d) acc += s_z[d] * prob_W[d];
    probs[(size_t)b * L_ + l] = acc;
  }
}

template <bool TANH, bool FINAL>
__global__ void __launch_bounds__(256) k_conv(const float* __restrict__ x,
    const float* __restrict__ w, const float* __restrict__ gamma,
    const float* __restrict__ beta, float* __restrict__ y,
    const float* __restrict__ res, float* __restrict__ out0,
    const int Cin, const int Cout) {
  const int b = blockIdx.x;
  const int co0 = blockIdx.y * 8;
  const int tid = threadIdx.x;
  const int l = tid & 127;
  const int cg = tid >> 7;
  __shared__ float s_x[8][260];
  __shared__ float s_w[8][8][5];
  float acc[4][2] = {{0.f, 0.f}, {0.f, 0.f}, {0.f, 0.f}, {0.f, 0.f}};
  for (int ci0 = 0; ci0 < Cin; ci0 += 8) {
    __syncthreads();
    for (int i = tid; i < 8 * 260; i += 256) {
      const int ci = i / 260, col = i % 260;
      const int ll = col - 2;
      s_x[ci][col] = (ll >= 0 && ll < L_) ? x[((size_t)b * Cin + ci0 + ci) * L_ + ll] : 0.f;
    }
    for (int i = tid; i < 8 * 8 * 5; i += 256) {
      const int ci = i / 40, rem = i % 40, cl = rem / 5, k = rem % 5;
      s_w[ci][cl][k] = w[((size_t)(co0 + cl) * Cin + ci0 + ci) * 5 + k];
    }
    __syncthreads();
#pragma unroll 2
    for (int ci = 0; ci < 8; ++ci) {
      float xv0[5], xv1[5];
#pragma unroll
      for (int k = 0; k < 5; ++k) { xv0[k] = s_x[ci][l + k]; xv1[k] = s_x[ci][l + 128 + k]; }
#pragma unroll
      for (int j = 0; j < 4; ++j) {
        const int cl = cg * 4 + j;
#pragma unroll
        for (int k = 0; k < 5; ++k) {
          const float ww = s_w[ci][cl][k];
          acc[j][0] += ww * xv0[k];
          acc[j][1] += ww * xv1[k];
        }
      }
    }
  }
#pragma unroll
  for (int j = 0; j < 4; ++j) {
    const int co = co0 + cg * 4 + j;
    const float gm = gamma[co], bt = beta[co];
#pragma unroll
    for (int h = 0; h < 2; ++h) {
      const int ll = l + h * 128;
      if (ll < L_) {
        float v = gm * acc[j][h] + bt;
        if (TANH) v = ftanh(v);
        if (FINAL) out0[((size_t)b * L_ + ll) * ODIM + co] =
                       res[((size_t)b * ODIM + co) * L_ + ll] + v;
        else y[((size_t)b * Cout + co) * L_ + ll] = v;
      }
    }
  }
}

// ---------------- launch ----------------

extern "C" void kernel_launch(void* const* d_in, const int* in_sizes, int n_in,
                              void* d_out, int out_size, void* d_ws, size_t ws_size,
                              hipStream_t stream) {
  const float* hs    = (const float*)d_in[0];
  const int*   hlens = (const int*)d_in[1];
  const float* ys    = (const float*)d_in[2];
  const float* W_enc = (const float*)d_in[3];
  const float* b_enc = (const float*)d_in[4];
  const float* W_dec = (const float*)d_in[5];
  const float* W_att = (const float*)d_in[6];
  const float* lconv = (const float*)d_in[7];
  const float* gvw   = (const float*)d_in[8];
  const float* pW1   = (const float*)d_in[10];
  const float* pW2   = (const float*)d_in[11];
  const float* Wih0  = (const float*)d_in[12];
  const float* Whh0  = (const float*)d_in[13];
  const float* b0    = (const float*)d_in[14];
  const float* Wih1  = (const float*)d_in[15];
  const float* Whh1  = (const float*)d_in[16];
  const float* b1    = (const float*)d_in[17];
  const float* featW = (const float*)d_in[18];
  const float* probW = (const float*)d_in[19];
  const float* probB = (const float*)d_in[20];
  const float* pwin  = (const float*)d_in[21];
  const float* pgin  = (const float*)d_in[22];
  const float* pbin  = (const float*)d_in[23];
  const float* pwmid = (const float*)d_in[24];
  const float* pgmid = (const float*)d_in[25];
  const float* pbmid = (const float*)d_in[26];
  const float* pwout = (const float*)d_in[27];
  const float* pgout = (const float*)d_in[28];
  const float* pbout = (const float*)d_in[29];

  char* ws = (char*)d_ws;
  h16*   pe_h   = (h16*)(ws + OFF_PE);
  h16*   h0h    = (h16*)(ws + OFF_H0H);
  h16*   z1h    = (h16*)(ws + OFF_Z1H);
  h16*   attc_h = (h16*)(ws + OFF_ATTC);
  float* c0     = (float*)(ws + OFF_C0);
  float* c1     = (float*)(ws + OFF_C1);
  float* gh0    = (float*)(ws + OFF_GH0);
  float* gz1    = (float*)(ws + OFF_GZ1);
  float* attw   = (float*)(ws + OFF_ATTW);
  h16*   Mb     = (h16*)(ws + OFF_MB);
  h16*   Wdh    = (h16*)(ws + OFF_WDH);
  h16*   pren_h = (h16*)(ws + OFF_PREN);
  h16*   hs_h   = (h16*)(ws + OFF_HSH);
  h16*   W0ah   = (h16*)(ws + OFF_W0AH);
  h16*   Whh0h  = (h16*)(ws + OFF_WHH0);
  h16*   Wz01h  = (h16*)(ws + OFF_WI1);
  h16*   Whh1h  = (h16*)(ws + OFF_WHH1);
  float* z1all  = (float*)(ws + OFF_Z1ALL);
  float* outsb  = (float*)(ws + OFF_OUTS);
  float* pa     = (float*)(ws + OFF_PA);
  float* pb     = (float*)(ws + OFF_PB);

  float* out0 = (float*)d_out;
  float* out1 = out0 + (size_t)B_ * L_ * ODIM;
  float* out2 = out1 + (size_t)B_ * L_ * ODIM;

  // prep
  hipLaunchKernelGGL(k_zero, dim3((ZERO_BYTES / 16 + 255) / 256), dim3(256), 0, stream,
                     (float4*)ws, (int)(ZERO_BYTES / 16));
  hipLaunchKernelGGL(k_attw0, dim3(B_), dim3(256), 0, stream, hlens, attw);
  hipLaunchKernelGGL(k_preenc, dim3(B_ * T_), dim3(128), 0, stream, hs, W_enc, b_enc, pe_h);
  hipLaunchKernelGGL(k_precMb, dim3(8), dim3(64), 0, stream, lconv, W_att, Mb);
  hipLaunchKernelGGL(k_cvt_perm, dim3(4096), dim3(256), 0, stream, Wih0, W0ah, 768);
  hipLaunchKernelGGL(k_cvt_perm, dim3(4096), dim3(256), 0, stream, Whh0, Whh0h, 1024);
  hipLaunchKernelGGL(k_cvt_perm, dim3(4096), dim3(256), 0, stream, Wih1, Wz01h, 1024);
  hipLaunchKernelGGL(k_cvt_perm, dim3(4096), dim3(256), 0, stream, Whh1, Whh1h, 1024);
  hipLaunchKernelGGL(k_cvt_f32f16, dim3(128), dim3(256), 0, stream, W_dec, Wdh);
  hipLaunchKernelGGL(k_cvt_f32f16, dim3(1600), dim3(256), 0, stream, hs, hs_h);
  hipLaunchKernelGGL(k_prenet1, dim3(B_ * L_), dim3(PRE), 0, stream, ys, pW1, pa);
  hipLaunchKernelGGL(k_prenet2h, dim3(B_ * L_), dim3(PRE), 0, stream, pa, pW2, pren_h);

  constexpr int BD = B_ * DUNITS;
  constexpr int BT = B_ * T_;

  // att(0): z0 = zeros (h0h buf0), attw buf0 -> buf1
  {
    const AttP P{pe_h, Mb, Wdh, hs_h, gvw, hlens, h0h, attw, attw + BT, attc_h};
    hipLaunchKernelGGL(k_att, dim3(B_), dim3(256), 0, stream, P);
  }

  // scan: 2 launches per step, dependencies carried by launch order only
  for (int t = 0; t < L_; ++t) {
    const int pi = t & 1, po = 1 - pi;
    hipLaunchKernelGGL(k_step1, dim3(512), dim3(256), 0, stream,
                       W0ah, Whh1h, attc_h, pren_h + (size_t)t * (B_ * PRE),
                       z1h + (size_t)pi * BD, gh0, gz1,
                       h0h + (size_t)po * BD, c0, b0);
    const AttP P{pe_h, Mb, Wdh, hs_h, gvw, hlens,
                 h0h + (size_t)po * BD, attw + (size_t)po * BT, attw + (size_t)pi * BT,
                 attc_h};
    hipLaunchKernelGGL(k_step2, dim3(528), dim3(256), 0, stream,
                       Wz01h, Whh0h, h0h + (size_t)po * BD, gz1, gh0,
                       z1h + (size_t)po * BD, c1, b1, z1all + (size_t)t * BD,
                       P, (t + 1 < L_) ? 1 : 0);
  }

  hipLaunchKernelGGL(k_heads, dim3(B_ * L_), dim3(128), 0, stream,
                     z1all, featW, probW, probB, out1, out2, outsb);

  hipLaunchKernelGGL((k_conv<true, false>), dim3(B_, 64), dim3(256), 0, stream,
                     outsb, pwin, pgin, pbin, pa, nullptr, nullptr, ODIM, 512);
  hipLaunchKernelGGL((k_conv<true, false>), dim3(B_, 64), dim3(256), 0, stream,
                     pa, pwmid, pgmid, pbmid, pb, nullptr, nullptr, 512, 512);
  hipLaunchKernelGGL((k_conv<true, false>), dim3(B_, 64), dim3(256), 0, stream,
                     pb, pwmid + (size_t)512 * 512 * 5, pgmid + 512, pbmid + 512,
                     pa, nullptr, nullptr, 512, 512);
  hipLaunchKernelGGL((k_conv<true, false>), dim3(B_, 64), dim3(256), 0, stream,
                     pa, pwmid + (size_t)2 * 512 * 512 * 5, pgmid + 1024, pbmid + 1024,
                     pb, nullptr, nullptr, 512, 512);
  hipLaunchKernelGGL((k_conv<false, true>), dim3(B_, 10), dim3(256), 0, stream,
                     pb, pwout, pgout, pbout, nullptr, outsb, out0, 512, ODIM);
}